// Round 13
// baseline (1291.254 us; speedup 1.0000x reference)
//
#include <hip/hip_runtime.h>
#include <hip/hip_bf16.h>
#include <stdint.h>

// SNN forward (snntorch Leaky, subtract reset), T=1024 B=128 NIN=256 HID=1024.
// d_out: out_spikes [T,B,2] | hidden_spikes [T,B,HID] | mem2_f [B,2]
//
// Round-13: R12 showed 36% of k_snn elapsed uncovered by any pipe — the LDS
// phase is a runtime-bounded loop, so the compiler emits per-dword
// ds_read->lgkmcnt->add with exposed latency. Fix: 3-deep software pipeline
// for the LDS phase (issue dword k+1..k+3's b128 reads before consuming
// dword k), mirroring the WISS/WCON VMEM window. Consume order stays strictly
// ascending-kd -> per-(t,j) add order unchanged -> bit-exact.
// Everything else identical to R12 (absmax 0.0 across rounds 1-12).

#define TT  1024
#define BB  128
#define NIN 256
#define HID 1024

#define OFF_HID  262144ULL
#define OFF_MEM2 134479872ULL

typedef float f2 __attribute__((ext_vector_type(2)));

// W1T gets 257 rows: rows 0..255 = transpose, row 256 = zeros (predication pad)
__global__ __launch_bounds__(256) void k_transpose(const float* __restrict__ W1,
                                                   float* __restrict__ W1T) {
    int idx = blockIdx.x * 256 + threadIdx.x;     // 263168 = 257*1024 elements
    if (idx >= 257 * 1024) return;
    int j = idx & (HID - 1);
    int i = idx >> 10;
    W1T[(size_t)i * HID + j] = (i < NIN) ? W1[(size_t)j * NIN + i] : 0.0f;
}

__global__ __launch_bounds__(256) void k_pack(const float* __restrict__ x,
                                              unsigned int* __restrict__ cntArr,
                                              unsigned char* __restrict__ idxArr,
                                              int slots) {
    size_t tb = blockIdx.x;                       // T*B blocks, 256 threads = i
    int tid = threadIdx.x;
    int lane = tid & 63, w = tid >> 6;
    float v = x[tb * NIN + tid];
    bool act = v > 0.5f;
    unsigned long long m = __ballot(act);
    __shared__ unsigned int wc[4];
    __shared__ unsigned char sIdx[96];
    if (lane == 0) wc[w] = (unsigned int)__popcll(m);
    __syncthreads();
    unsigned int off = 0;
#pragma unroll
    for (int k = 0; k < 4; ++k) if (k < w) off += wc[k];
    unsigned int cnt = wc[0] + wc[1] + wc[2] + wc[3];
    unsigned int rank = off + (unsigned int)__popcll(m & ((1ull << lane) - 1));
    if (act && rank < (unsigned int)slots) sIdx[rank] = (unsigned char)tid;
    __syncthreads();
    if (tid * 4 < slots)
        ((unsigned int*)(idxArr + tb * (size_t)slots))[tid] = ((const unsigned int*)sIdx)[tid];
    if (tid == 0) cntArr[tb] = cnt;
}

// Workgroup = 4 waves = 4 b's sharing a 64-j chunk of W1T as [257 i][16 quads]
// float4 (64.3 KB LDS). lane = (s=lane>>4 t-subgroup, q=lane&15 quad).
// Grid = 32 bg x 16 jc = 512 wgs -> 2 wg/CU, 2 waves/SIMD.
__global__ __launch_bounds__(256, 2) void k_snn(const float* __restrict__ W1T,
                                                const unsigned int* __restrict__ cntArr,
                                                const unsigned char* __restrict__ idxArr,
                                                const float* __restrict__ x,
                                                const float* __restrict__ b1,
                                                float* __restrict__ outHid,
                                                int slots) {
#pragma clang fp contract(off)
    const int jc   = blockIdx.x & 15;
    const int bg   = blockIdx.x >> 4;
    const int tid  = threadIdx.x;
    const int lane = tid & 63;
    const int wave = tid >> 6;
    const int b    = (bg << 2) + wave;
    const int q    = lane & 15;                   // quad (4 j) within 64-j chunk
    const int s    = lane >> 4;                   // t-subgroup 0..3
    const int jq   = (jc << 6) + (q << 2);
    const int jq4  = jq >> 2;                     // float4 index of lane's quad

    __shared__ float4 sW4[257 * 16];              // 64.3 KB; row 256 = zeros
    __shared__ float4 sEx[4][64];                 // per-wave exchange scratch

    for (int p = tid; p < NIN * 16; p += 256) {
        int i = p >> 4, qq = p & 15;
        sW4[p] = *reinterpret_cast<const float4*>(W1T + (size_t)i * HID + (jc << 6) + (qq << 2));
    }
    if (tid < 16) sW4[256 * 16 + tid] = make_float4(0.f, 0.f, 0.f, 0.f);
    __syncthreads();

    f2 mem01, mem23;
    mem01.x = 0.f; mem01.y = 0.f; mem23.x = 0.f; mem23.y = 0.f;
    const float4 bs = *reinterpret_cast<const float4*>(b1 + jq);
    const int ub = __builtin_amdgcn_readfirstlane(b);
    const int sl = slots;
    const int dwTot = sl >> 2;
    int dwA = q;            if (dwA >= dwTot) dwA = dwTot - 1;
    int dwB = 16 + (q & 7); if (dwB >= dwTot) dwB = dwTot - 1;

    const bool sLo   = (s < 2);
    const bool sEven = ((s & 1) == 0);
    const float4* __restrict__ W1Tf4 = reinterpret_cast<const float4*>(W1T);

    // strength-reduced prefetch offsets (bytes), pointing at t = 0..3
    unsigned offCnt = (unsigned)((s * BB + ub) * 4);
    unsigned offA   = (unsigned)((s * BB + ub) * sl + dwA * 4);
    unsigned offB   = (unsigned)((s * BB + ub) * sl + dwB * 4);
    const unsigned stC = (unsigned)(4 * BB * 4);
    const unsigned stL = (unsigned)(4 * BB * sl);

    unsigned cnt_v = *(const unsigned*)((const char*)cntArr + offCnt);
    unsigned vA_v  = *(const unsigned*)(idxArr + offA);
    unsigned vB_v  = *(const unsigned*)(idxArr + offB);

    float* outP = outHid + ((size_t)s * BB + b) * HID + jq;
    const size_t outStep = (size_t)4 * BB * HID;

#define RL(v, l) ((unsigned)__builtin_amdgcn_readlane((int)(v), (l)))
    // full fetch (kd may be >=16): used by WISS
#define FETCH_D(kd, dOut) do {                                                  \
        unsigned _d0, _d1, _d2, _d3;                                            \
        if ((kd) < 16) {                                                        \
            _d0 = RL(vA, (kd));      _d1 = RL(vA, 16 + (kd));                   \
            _d2 = RL(vA, 32 + (kd)); _d3 = RL(vA, 48 + (kd));                   \
        } else { int _m = (kd) - 16;                                            \
            _d0 = RL(vB, _m);        _d1 = RL(vB, 16 + _m);                     \
            _d2 = RL(vB, 32 + _m);   _d3 = RL(vB, 48 + _m); }                   \
        unsigned _dl = sEven ? _d0 : _d1;                                       \
        unsigned _dh = sEven ? _d2 : _d3;                                       \
        dOut = sLo ? _dl : _dh;                                                 \
    } while (0)

    // LDS-phase fetch: kd < SPLIT(9) <= 15 always -> vA only, no 16-branch
#define FETCH_A(kd, dOut) do {                                                  \
        unsigned _d0 = RL(vA, (kd));      unsigned _d1 = RL(vA, 16 + (kd));     \
        unsigned _d2 = RL(vA, 32 + (kd)); unsigned _d3 = RL(vA, 48 + (kd));     \
        unsigned _dl = sEven ? _d0 : _d1;                                       \
        unsigned _dh = sEven ? _d2 : _d3;                                       \
        dOut = sLo ? _dl : _dh;                                                 \
    } while (0)

    // --- LDS-phase 3-deep pipeline: issue one dword's 4 b128 reads into reg
    // set X (La/Lb/Lc); predication only past predFrom (wave-uniform branch).
#define LISS(X) do {                                                            \
        if (liss < dwL) {                                                       \
            unsigned d_; FETCH_A(liss, d_);                                     \
            unsigned r0_ = d_ & 255u, r1_ = (d_ >> 8) & 255u;                   \
            unsigned r2_ = (d_ >> 16) & 255u, r3_ = d_ >> 24;                   \
            if (liss >= predFrom) {                                             \
                int kb_ = liss << 2;                                            \
                r0_ = ((unsigned)(kb_    ) < mylim) ? r0_ : 256u;               \
                r1_ = ((unsigned)(kb_ + 1) < mylim) ? r1_ : 256u;               \
                r2_ = ((unsigned)(kb_ + 2) < mylim) ? r2_ : 256u;               \
                r3_ = ((unsigned)(kb_ + 3) < mylim) ? r3_ : 256u;               \
            }                                                                   \
            X##p = sW4[r0_ * 16 + q];                                           \
            X##r = sW4[r1_ * 16 + q];                                           \
            X##s = sW4[r2_ * 16 + q];                                           \
            X##t = sW4[r3_ * 16 + q];                                           \
            ++liss;                                                             \
        }                                                                       \
    } while (0)

#define PKADD(vv) do {                                                          \
        f2 ta_; ta_.x = vv.x; ta_.y = vv.y;                                     \
        f2 tb_; tb_.x = vv.z; tb_.y = vv.w;                                     \
        h01 += ta_;  h23 += tb_;                                                \
    } while (0)

#define LCON(X) do { PKADD(X##p); PKADD(X##r); PKADD(X##s); PKADD(X##t); } while (0)

    // issue one dword's 4 global float4 loads into window slot n; predication
    // only past kmin (wave-uniform branch)
#define WISS(n) do {                                                            \
        if (isu < dwEnd) {                                                      \
            unsigned d_; FETCH_D(isu, d_);                                      \
            unsigned r0_ = d_ & 255u, r1_ = (d_ >> 8) & 255u;                   \
            unsigned r2_ = (d_ >> 16) & 255u, r3_ = d_ >> 24;                   \
            if (isu >= predFrom) {                                              \
                int kb_ = isu << 2;                                             \
                r0_ = ((unsigned)(kb_    ) < mylim) ? r0_ : 256u;               \
                r1_ = ((unsigned)(kb_ + 1) < mylim) ? r1_ : 256u;               \
                r2_ = ((unsigned)(kb_ + 2) < mylim) ? r2_ : 256u;               \
                r3_ = ((unsigned)(kb_ + 3) < mylim) ? r3_ : 256u;               \
            }                                                                   \
            w##n##a = W1Tf4[(r0_ << 8) + jq4];                                  \
            w##n##b = W1Tf4[(r1_ << 8) + jq4];                                  \
            w##n##c = W1Tf4[(r2_ << 8) + jq4];                                  \
            w##n##d = W1Tf4[(r3_ << 8) + jq4];                                  \
            ++isu;                                                              \
        }                                                                       \
    } while (0)

#define WCON(n) do { PKADD(w##n##a); PKADD(w##n##b); PKADD(w##n##c); PKADD(w##n##d); } while (0)

    const int SPLIT = 9;                          // dwords via LDS (k < 36)

    for (int t = 0; t < TT; t += 4) {
        unsigned cnt = cnt_v, vA = vA_v, vB = vB_v;

        // prefetch t+4 (clamped via zero stride on last iter)
        unsigned st = (t + 4 < TT) ? 1u : 0u;
        offCnt += st * stC; offA += st * stL; offB += st * stL;
        cnt_v = *(const unsigned*)((const char*)cntArr + offCnt);
        vA_v  = *(const unsigned*)(idxArr + offA);
        vB_v  = *(const unsigned*)(idxArr + offB);

        unsigned mylim = cnt < (unsigned)sl ? cnt : (unsigned)sl;
        int l0 = __builtin_amdgcn_readlane((int)mylim, 0);
        int l1 = __builtin_amdgcn_readlane((int)mylim, 16);
        int l2 = __builtin_amdgcn_readlane((int)mylim, 32);
        int l3 = __builtin_amdgcn_readlane((int)mylim, 48);
        int kmax = l0 > l1 ? l0 : l1; kmax = kmax > l2 ? kmax : l2; kmax = kmax > l3 ? kmax : l3;
        int kmin = l0 < l1 ? l0 : l1; kmin = kmin < l2 ? kmin : l2; kmin = kmin < l3 ? kmin : l3;

        int dwEnd = (kmax + 3) >> 2;
        int dwL   = dwEnd < SPLIT ? dwEnd : SPLIT;
        int predFrom = kmin >> 2;

        float4 e0, e1, e2, e3;                    // h(t+0..t+3) for quad q

        if (!__any((int)(cnt > (unsigned)sl))) {
            f2 h01, h23;
            h01.x = bs.x; h01.y = bs.y; h23.x = bs.z; h23.y = bs.w;

            // ---- issue-ahead window: 4 dwords of global loads in flight ----
            float4 w0a, w0b, w0c, w0d;
            float4 w1a, w1b, w1c, w1d;
            float4 w2a, w2b, w2c, w2d;
            float4 w3a, w3b, w3c, w3d;
            int isu = SPLIT;
            WISS(0); WISS(1); WISS(2); WISS(3);

            // ---- LDS phase: 3-deep pipelined, consume ascending-kd ----
            float4 Lap, Lar, Las, Lat;
            float4 Lbp, Lbr, Lbs, Lbt;
            float4 Lcp, Lcr, Lcs, Lct;
            int liss = 0;
            LISS(La); LISS(Lb); LISS(Lc);
            int kd = 0;
            for (; kd + 3 <= dwL; kd += 3) {
                LCON(La); LISS(La);
                LCON(Lb); LISS(Lb);
                LCON(Lc); LISS(Lc);
            }
            {
                int lrem = dwL - kd;
                if (lrem > 0) LCON(La);
                if (lrem > 1) LCON(Lb);
                if (lrem > 2) LCON(Lc);
            }

            // ---- consume window 4-wide, reissue as we go ----
            int kc = SPLIT;
            for (; kc + 4 <= dwEnd; kc += 4) {
                WCON(0); WISS(0);
                WCON(1); WISS(1);
                WCON(2); WISS(2);
                WCON(3); WISS(3);
            }
            int rem = dwEnd - kc;
            if (rem > 0) WCON(0);
            if (rem > 1) WCON(1);
            if (rem > 2) WCON(2);

            // exchange: every lane gets h(t+0..t+3) for its quad
            sEx[wave][lane] = make_float4(h01.x, h01.y, h23.x, h23.y);
            e0 = sEx[wave][q];
            e1 = sEx[wave][16 + q];
            e2 = sEx[wave][32 + q];
            e3 = sEx[wave][48 + q];
        } else {
            // ~never: some count exceeds slots -> recompute all 4 t's from x
#pragma unroll
            for (int tt = 0; tt < 4; ++tt) {
                const float* xr = x + ((size_t)(t + tt) * BB + ub) * NIN;
                float g0 = bs.x, g1 = bs.y, g2 = bs.z, g3 = bs.w;
                for (int w2 = 0; w2 < 4; ++w2) {
                    unsigned long long m = __ballot(xr[(w2 << 6) + lane] > 0.5f);
                    while (m) {
                        int i = (w2 << 6) + __builtin_ctzll(m);
                        m &= m - 1;
                        float4 v = sW4[i * 16 + q];
                        g0 += v.x; g1 += v.y; g2 += v.z; g3 += v.w;
                    }
                }
                if      (tt == 0) e0 = make_float4(g0, g1, g2, g3);
                else if (tt == 1) e1 = make_float4(g0, g1, g2, g3);
                else if (tt == 2) e2 = make_float4(g0, g1, g2, g3);
                else              e3 = make_float4(g0, g1, g2, g3);
            }
        }

        // 4 membrane steps (np fp32 semantics: mul, add separate; packed ops
        // are per-slot IEEE fp32 -> bit-identical), redundant across lanes.
#define MSTEP4(ev, so0, so1, so2, so3) {                                        \
        f2 ha_, hb_, mmA_, mmB_, sp_;                                           \
        ha_.x = ev.x; ha_.y = ev.y; hb_.x = ev.z; hb_.y = ev.w;                 \
        mmA_ = 0.9f * mem01; mmA_ = mmA_ + ha_;                                 \
        so0 = (mmA_.x - 1.0f > 0.0f) ? 1.0f : 0.0f;                             \
        so1 = (mmA_.y - 1.0f > 0.0f) ? 1.0f : 0.0f;                             \
        sp_.x = so0; sp_.y = so1; mem01 = mmA_ - sp_;                           \
        mmB_ = 0.9f * mem23; mmB_ = mmB_ + hb_;                                 \
        so2 = (mmB_.x - 1.0f > 0.0f) ? 1.0f : 0.0f;                             \
        so3 = (mmB_.y - 1.0f > 0.0f) ? 1.0f : 0.0f;                             \
        sp_.x = so2; sp_.y = so3; mem23 = mmB_ - sp_;                           \
    }
        float sA0, sA1, sA2, sA3, sB0, sB1, sB2, sB3;
        float sC0, sC1, sC2, sC3, sD0, sD1, sD2, sD3;
        MSTEP4(e0, sA0, sA1, sA2, sA3)
        MSTEP4(e1, sB0, sB1, sB2, sB3)
        MSTEP4(e2, sC0, sC1, sC2, sC3)
        MSTEP4(e3, sD0, sD1, sD2, sD3)
#undef MSTEP4

        // lane stores its own group's row (t+s)
        float4 sv;
        sv.x = sLo ? (sEven ? sA0 : sB0) : (sEven ? sC0 : sD0);
        sv.y = sLo ? (sEven ? sA1 : sB1) : (sEven ? sC1 : sD1);
        sv.z = sLo ? (sEven ? sA2 : sB2) : (sEven ? sC2 : sD2);
        sv.w = sLo ? (sEven ? sA3 : sB3) : (sEven ? sC3 : sD3);
        *reinterpret_cast<float4*>(outP) = sv;
        outP += outStep;
    }
#undef WCON
#undef WISS
#undef LCON
#undef LISS
#undef PKADD
#undef FETCH_A
#undef FETCH_D
#undef RL
}

// One wave per (t,b): bit-identical layer-2 tree to rounds 1-12:
// per chunk c (ascending 0..15): r = spk[c*64+lane]*W2[o][c*64+lane],
// xor-butterfly offs 32,16,8,4,2,1, accumulate; then + b2[o].
__global__ __launch_bounds__(256) void k_h2(const float* __restrict__ spk,
                                            const float* __restrict__ W2,
                                            const float* __restrict__ b2,
                                            float* __restrict__ h2) {
#pragma clang fp contract(off)
    const int lane = threadIdx.x & 63;
    const int wave = threadIdx.x >> 6;
    size_t tb = (size_t)blockIdx.x * 4 + wave;    // t*B + b
    const float* row = spk + tb * HID;
    float s0 = 0.0f, s1 = 0.0f;
#pragma unroll
    for (int c = 0; c < 16; ++c) {
        float v  = row[c * 64 + lane];
        float r0 = v * W2[c * 64 + lane];
        float r1 = v * W2[HID + c * 64 + lane];
#pragma unroll
        for (int off = 32; off > 0; off >>= 1) {
            r0 += __shfl_xor(r0, off, 64);
            r1 += __shfl_xor(r1, off, 64);
        }
        s0 += r0;
        s1 += r1;
    }
    s0 += b2[0];
    s1 += b2[1];
    if (lane == 0)
        *reinterpret_cast<float2*>(h2 + tb * 2) = make_float2(s0, s1);
}

__global__ __launch_bounds__(256) void k_scan(const float* __restrict__ h2,
                                              float* __restrict__ outSpk,
                                              float* __restrict__ outMem2) {
#pragma clang fp contract(off)
    const int tid = threadIdx.x;                  // b*2 + o
    float mem = 0.0f;
    float cur[8], nxt[8];
#pragma unroll
    for (int k = 0; k < 8; ++k) cur[k] = h2[k * 256 + tid];
    for (int t0 = 0; t0 < TT; t0 += 8) {
#pragma unroll
        for (int k = 0; k < 8; ++k) {
            int tn = t0 + 8 + k;
            nxt[k] = (tn < TT) ? h2[tn * 256 + tid] : 0.0f;
        }
#pragma unroll
        for (int k = 0; k < 8; ++k) {
            float mm = 0.9f * mem;
            mm = mm + cur[k];
            float spk = (mm - 1.0f > 0.0f) ? 1.0f : 0.0f;
            mm = mm - spk;
            mem = mm;
            outSpk[(t0 + k) * 256 + tid] = spk;
        }
#pragma unroll
        for (int k = 0; k < 8; ++k) cur[k] = nxt[k];
    }
    outMem2[tid] = mem;
}

extern "C" void kernel_launch(void* const* d_in, const int* in_sizes, int n_in,
                              void* d_out, int out_size, void* d_ws, size_t ws_size,
                              hipStream_t stream) {
    const float* x  = (const float*)d_in[0];
    const float* W1 = (const float*)d_in[1];
    const float* b1 = (const float*)d_in[2];
    const float* W2 = (const float*)d_in[3];
    const float* b2 = (const float*)d_in[4];
    float* out = (float*)d_out;

    char* ws = (char*)d_ws;
    float*         W1T = (float*)(ws);                                 // 257 rows ~1.03 MB
    unsigned int*  cnt = (unsigned int*)(ws + (2 << 20));              // 512 KB
    unsigned char* idx = (unsigned char*)(ws + (2 << 20) + (1 << 19)); // 131072*slots

    // size the index lists to the workspace (fallback path covers overflow)
    size_t fixedB = (size_t)(2 << 20) + (1 << 19) + (1 << 20);
    size_t avail  = ws_size > fixedB ? ws_size - fixedB : 0;
    long   s      = (long)((avail / 131072) & ~(size_t)7);
    int slots = (int)(s > 96 ? 96 : (s < 8 ? 8 : s));

    float* h2 = (float*)(ws + (2 << 20) + (1 << 19) + (size_t)131072 * (size_t)slots); // 1 MB

    k_transpose<<<1028, 256, 0, stream>>>(W1, W1T);
    k_pack<<<131072, 256, 0, stream>>>(x, cnt, idx, slots);
    k_snn<<<512, 256, 0, stream>>>(W1T, cnt, idx, x, b1, out + OFF_HID, slots);
    k_h2<<<32768, 256, 0, stream>>>(out + OFF_HID, W2, b2, h2);
    k_scan<<<1, 256, 0, stream>>>(h2, out, out + OFF_MEM2);
}

// Round 14
// 1201.851 us; speedup vs baseline: 1.0744x; 1.0744x over previous
//
#include <hip/hip_runtime.h>
#include <hip/hip_bf16.h>
#include <stdint.h>

// SNN forward (snntorch Leaky, subtract reset), T=1024 B=128 NIN=256 HID=1024.
// d_out: out_spikes [T,B,2] | hidden_spikes [T,B,HID] | mem2_f [B,2]
//
// Round-14: revert R13's LDS pipeline (regressed: per-issue branches + reg
// pressure > latency hidden). R12 skeleton with native ext_vector f4 types
// everywhere: ds_read_b128 / global_load_dwordx4 results are aligned VGPR
// quads, and f4 += f4 lowers to 2x v_pk_add_f32 with ZERO marshaling movs
// (R12 built f2s element-wise from float4 -> mov-heavy, why pk only gave 4%).
// Membrane in pk form too (scalar compares). Per-slot IEEE fp32, per-(t,j)
// chains stay bias -> strictly ascending active i -> bit-exact (absmax 0.0
// across rounds 1-13). k_pack/k_h2/k_scan/k_transpose unchanged.

#define TT  1024
#define BB  128
#define NIN 256
#define HID 1024

#define OFF_HID  262144ULL
#define OFF_MEM2 134479872ULL

typedef float f4 __attribute__((ext_vector_type(4)));

// W1T gets 257 rows: rows 0..255 = transpose, row 256 = zeros (predication pad)
__global__ __launch_bounds__(256) void k_transpose(const float* __restrict__ W1,
                                                   float* __restrict__ W1T) {
    int idx = blockIdx.x * 256 + threadIdx.x;     // 263168 = 257*1024 elements
    if (idx >= 257 * 1024) return;
    int j = idx & (HID - 1);
    int i = idx >> 10;
    W1T[(size_t)i * HID + j] = (i < NIN) ? W1[(size_t)j * NIN + i] : 0.0f;
}

__global__ __launch_bounds__(256) void k_pack(const float* __restrict__ x,
                                              unsigned int* __restrict__ cntArr,
                                              unsigned char* __restrict__ idxArr,
                                              int slots) {
    size_t tb = blockIdx.x;                       // T*B blocks, 256 threads = i
    int tid = threadIdx.x;
    int lane = tid & 63, w = tid >> 6;
    float v = x[tb * NIN + tid];
    bool act = v > 0.5f;
    unsigned long long m = __ballot(act);
    __shared__ unsigned int wc[4];
    __shared__ unsigned char sIdx[96];
    if (lane == 0) wc[w] = (unsigned int)__popcll(m);
    __syncthreads();
    unsigned int off = 0;
#pragma unroll
    for (int k = 0; k < 4; ++k) if (k < w) off += wc[k];
    unsigned int cnt = wc[0] + wc[1] + wc[2] + wc[3];
    unsigned int rank = off + (unsigned int)__popcll(m & ((1ull << lane) - 1));
    if (act && rank < (unsigned int)slots) sIdx[rank] = (unsigned char)tid;
    __syncthreads();
    if (tid * 4 < slots)
        ((unsigned int*)(idxArr + tb * (size_t)slots))[tid] = ((const unsigned int*)sIdx)[tid];
    if (tid == 0) cntArr[tb] = cnt;
}

// Workgroup = 4 waves = 4 b's sharing a 64-j chunk of W1T as [257 i][16 quads]
// f4 (64.3 KB LDS). lane = (s=lane>>4 t-subgroup, q=lane&15 quad).
// Grid = 32 bg x 16 jc = 512 wgs -> 2 wg/CU, 2 waves/SIMD.
__global__ __launch_bounds__(256, 2) void k_snn(const float* __restrict__ W1T,
                                                const unsigned int* __restrict__ cntArr,
                                                const unsigned char* __restrict__ idxArr,
                                                const float* __restrict__ x,
                                                const float* __restrict__ b1,
                                                float* __restrict__ outHid,
                                                int slots) {
#pragma clang fp contract(off)
    const int jc   = blockIdx.x & 15;
    const int bg   = blockIdx.x >> 4;
    const int tid  = threadIdx.x;
    const int lane = tid & 63;
    const int wave = tid >> 6;
    const int b    = (bg << 2) + wave;
    const int q    = lane & 15;                   // quad (4 j) within 64-j chunk
    const int s    = lane >> 4;                   // t-subgroup 0..3
    const int jq   = (jc << 6) + (q << 2);
    const int jq4  = jq >> 2;                     // f4 index of lane's quad

    __shared__ f4 sW4[257 * 16];                  // 64.3 KB; row 256 = zeros
    __shared__ f4 sEx[4][64];                     // per-wave exchange scratch

    for (int p = tid; p < NIN * 16; p += 256) {
        int i = p >> 4, qq = p & 15;
        sW4[p] = *reinterpret_cast<const f4*>(W1T + (size_t)i * HID + (jc << 6) + (qq << 2));
    }
    if (tid < 16) { f4 z; z.x = 0.f; z.y = 0.f; z.z = 0.f; z.w = 0.f; sW4[256 * 16 + tid] = z; }
    __syncthreads();

    f4 mem4;
    mem4.x = 0.f; mem4.y = 0.f; mem4.z = 0.f; mem4.w = 0.f;
    const f4 bs = *reinterpret_cast<const f4*>(b1 + jq);
    const int ub = __builtin_amdgcn_readfirstlane(b);
    const int sl = slots;
    const int dwTot = sl >> 2;
    int dwA = q;            if (dwA >= dwTot) dwA = dwTot - 1;
    int dwB = 16 + (q & 7); if (dwB >= dwTot) dwB = dwTot - 1;

    const bool sLo   = (s < 2);
    const bool sEven = ((s & 1) == 0);
    const f4* __restrict__ W1Tf4 = reinterpret_cast<const f4*>(W1T);

    // strength-reduced prefetch offsets (bytes), pointing at t = 0..3
    unsigned offCnt = (unsigned)((s * BB + ub) * 4);
    unsigned offA   = (unsigned)((s * BB + ub) * sl + dwA * 4);
    unsigned offB   = (unsigned)((s * BB + ub) * sl + dwB * 4);
    const unsigned stC = (unsigned)(4 * BB * 4);
    const unsigned stL = (unsigned)(4 * BB * sl);

    unsigned cnt_v = *(const unsigned*)((const char*)cntArr + offCnt);
    unsigned vA_v  = *(const unsigned*)(idxArr + offA);
    unsigned vB_v  = *(const unsigned*)(idxArr + offB);

    float* outP = outHid + ((size_t)s * BB + b) * HID + jq;
    const size_t outStep = (size_t)4 * BB * HID;

#define RL(v, l) ((unsigned)__builtin_amdgcn_readlane((int)(v), (l)))
    // full fetch (kd may be >=16): used by WISS
#define FETCH_D(kd, dOut) do {                                                  \
        unsigned _d0, _d1, _d2, _d3;                                            \
        if ((kd) < 16) {                                                        \
            _d0 = RL(vA, (kd));      _d1 = RL(vA, 16 + (kd));                   \
            _d2 = RL(vA, 32 + (kd)); _d3 = RL(vA, 48 + (kd));                   \
        } else { int _m = (kd) - 16;                                            \
            _d0 = RL(vB, _m);        _d1 = RL(vB, 16 + _m);                     \
            _d2 = RL(vB, 32 + _m);   _d3 = RL(vB, 48 + _m); }                   \
        unsigned _dl = sEven ? _d0 : _d1;                                       \
        unsigned _dh = sEven ? _d2 : _d3;                                       \
        dOut = sLo ? _dl : _dh;                                                 \
    } while (0)

    // LDS-phase fetch: kd < SPLIT(9) <= 15 always -> vA only, no 16-branch
#define FETCH_A(kd, dOut) do {                                                  \
        unsigned _d0 = RL(vA, (kd));      unsigned _d1 = RL(vA, 16 + (kd));     \
        unsigned _d2 = RL(vA, 32 + (kd)); unsigned _d3 = RL(vA, 48 + (kd));     \
        unsigned _dl = sEven ? _d0 : _d1;                                       \
        unsigned _dh = sEven ? _d2 : _d3;                                       \
        dOut = sLo ? _dl : _dh;                                                 \
    } while (0)

#define B_LDS(kd, PRED) do {                                                    \
        unsigned d_; FETCH_A(kd, d_);                                           \
        int kb_ = (kd) << 2;                                                    \
        _Pragma("unroll")                                                       \
        for (int i2 = 0; i2 < 4; ++i2) {                                        \
            unsigned row_ = (d_ >> (8 * i2)) & 255u;                            \
            if (PRED) row_ = ((unsigned)(kb_ + i2) < mylim) ? row_ : 256u;      \
            h4 += sW4[row_ * 16 + q];              /* 2x v_pk_add_f32, no movs */ \
        }                                                                       \
    } while (0)

    // issue one dword's 4 global f4 loads into window slot n; predication
    // only past kmin (wave-uniform branch)
#define WISS(n) do {                                                            \
        if (isu < dwEnd) {                                                      \
            unsigned d_; FETCH_D(isu, d_);                                      \
            unsigned r0_ = d_ & 255u, r1_ = (d_ >> 8) & 255u;                   \
            unsigned r2_ = (d_ >> 16) & 255u, r3_ = d_ >> 24;                   \
            if (isu >= predFrom) {                                              \
                int kb_ = isu << 2;                                             \
                r0_ = ((unsigned)(kb_    ) < mylim) ? r0_ : 256u;               \
                r1_ = ((unsigned)(kb_ + 1) < mylim) ? r1_ : 256u;               \
                r2_ = ((unsigned)(kb_ + 2) < mylim) ? r2_ : 256u;               \
                r3_ = ((unsigned)(kb_ + 3) < mylim) ? r3_ : 256u;               \
            }                                                                   \
            w##n##a = W1Tf4[(r0_ << 8) + jq4];                                  \
            w##n##b = W1Tf4[(r1_ << 8) + jq4];                                  \
            w##n##c = W1Tf4[(r2_ << 8) + jq4];                                  \
            w##n##d = W1Tf4[(r3_ << 8) + jq4];                                  \
            ++isu;                                                              \
        }                                                                       \
    } while (0)

#define WCON(n) do { h4 += w##n##a; h4 += w##n##b; h4 += w##n##c; h4 += w##n##d; } while (0)

    const int SPLIT = 9;                          // dwords via LDS (k < 36)

    for (int t = 0; t < TT; t += 4) {
        unsigned cnt = cnt_v, vA = vA_v, vB = vB_v;

        // prefetch t+4 (clamped via zero stride on last iter)
        unsigned st = (t + 4 < TT) ? 1u : 0u;
        offCnt += st * stC; offA += st * stL; offB += st * stL;
        cnt_v = *(const unsigned*)((const char*)cntArr + offCnt);
        vA_v  = *(const unsigned*)(idxArr + offA);
        vB_v  = *(const unsigned*)(idxArr + offB);

        unsigned mylim = cnt < (unsigned)sl ? cnt : (unsigned)sl;
        int l0 = __builtin_amdgcn_readlane((int)mylim, 0);
        int l1 = __builtin_amdgcn_readlane((int)mylim, 16);
        int l2 = __builtin_amdgcn_readlane((int)mylim, 32);
        int l3 = __builtin_amdgcn_readlane((int)mylim, 48);
        int kmax = l0 > l1 ? l0 : l1; kmax = kmax > l2 ? kmax : l2; kmax = kmax > l3 ? kmax : l3;
        int kmin = l0 < l1 ? l0 : l1; kmin = kmin < l2 ? kmin : l2; kmin = kmin < l3 ? kmin : l3;

        int dwEnd = (kmax + 3) >> 2;
        int dwL   = dwEnd < SPLIT ? dwEnd : SPLIT;
        int dwLm  = (kmin >> 2) < dwL ? (kmin >> 2) : dwL;
        int predFrom = kmin >> 2;

        f4 e0, e1, e2, e3;                        // h(t+0..t+3) for quad q

        if (!__any((int)(cnt > (unsigned)sl))) {
            f4 h4 = bs;

            // ---- issue-ahead window: 4 dwords of global loads in flight ----
            f4 w0a, w0b, w0c, w0d;
            f4 w1a, w1b, w1c, w1d;
            f4 w2a, w2b, w2c, w2d;
            f4 w3a, w3b, w3c, w3d;
            int isu = SPLIT;
            WISS(0); WISS(1); WISS(2); WISS(3);

            // ---- LDS phase: dwords 0..dwL (ascending-i adds) ----
            int kd = 0;
            for (; kd < dwLm; ++kd) B_LDS(kd, false);
            for (; kd < dwL;  ++kd) B_LDS(kd, true);

            // ---- consume window 4-wide, reissue as we go ----
            int kc = SPLIT;
            for (; kc + 4 <= dwEnd; kc += 4) {
                WCON(0); WISS(0);
                WCON(1); WISS(1);
                WCON(2); WISS(2);
                WCON(3); WISS(3);
            }
            int rem = dwEnd - kc;
            if (rem > 0) WCON(0);
            if (rem > 1) WCON(1);
            if (rem > 2) WCON(2);

            // exchange: every lane gets h(t+0..t+3) for its quad
            sEx[wave][lane] = h4;
            e0 = sEx[wave][q];
            e1 = sEx[wave][16 + q];
            e2 = sEx[wave][32 + q];
            e3 = sEx[wave][48 + q];
        } else {
            // ~never: some count exceeds slots -> recompute all 4 t's from x
#pragma unroll
            for (int tt = 0; tt < 4; ++tt) {
                const float* xr = x + ((size_t)(t + tt) * BB + ub) * NIN;
                f4 g = bs;
                for (int w2 = 0; w2 < 4; ++w2) {
                    unsigned long long m = __ballot(xr[(w2 << 6) + lane] > 0.5f);
                    while (m) {
                        int i = (w2 << 6) + __builtin_ctzll(m);
                        m &= m - 1;
                        g += sW4[i * 16 + q];
                    }
                }
                if      (tt == 0) e0 = g;
                else if (tt == 1) e1 = g;
                else if (tt == 2) e2 = g;
                else              e3 = g;
            }
        }

        // 4 membrane steps (np fp32 semantics: mul, add separate; packed ops
        // are per-slot IEEE fp32 -> bit-identical), redundant across lanes.
#define MSTEP4(ev, so0, so1, so2, so3) {                                        \
        f4 mm_ = 0.9f * mem4; mm_ = mm_ + (ev);                                 \
        so0 = (mm_.x - 1.0f > 0.0f) ? 1.0f : 0.0f;                              \
        so1 = (mm_.y - 1.0f > 0.0f) ? 1.0f : 0.0f;                              \
        so2 = (mm_.z - 1.0f > 0.0f) ? 1.0f : 0.0f;                              \
        so3 = (mm_.w - 1.0f > 0.0f) ? 1.0f : 0.0f;                              \
        f4 sp_; sp_.x = so0; sp_.y = so1; sp_.z = so2; sp_.w = so3;             \
        mem4 = mm_ - sp_;                                                       \
    }
        float sA0, sA1, sA2, sA3, sB0, sB1, sB2, sB3;
        float sC0, sC1, sC2, sC3, sD0, sD1, sD2, sD3;
        MSTEP4(e0, sA0, sA1, sA2, sA3)
        MSTEP4(e1, sB0, sB1, sB2, sB3)
        MSTEP4(e2, sC0, sC1, sC2, sC3)
        MSTEP4(e3, sD0, sD1, sD2, sD3)
#undef MSTEP4

        // lane stores its own group's row (t+s)
        f4 sv;
        sv.x = sLo ? (sEven ? sA0 : sB0) : (sEven ? sC0 : sD0);
        sv.y = sLo ? (sEven ? sA1 : sB1) : (sEven ? sC1 : sD1);
        sv.z = sLo ? (sEven ? sA2 : sB2) : (sEven ? sC2 : sD2);
        sv.w = sLo ? (sEven ? sA3 : sB3) : (sEven ? sC3 : sD3);
        *reinterpret_cast<f4*>(outP) = sv;
        outP += outStep;
    }
#undef WCON
#undef WISS
#undef B_LDS
#undef FETCH_A
#undef FETCH_D
#undef RL
}

// One wave per (t,b): bit-identical layer-2 tree to rounds 1-13:
// per chunk c (ascending 0..15): r = spk[c*64+lane]*W2[o][c*64+lane],
// xor-butterfly offs 32,16,8,4,2,1, accumulate; then + b2[o].
__global__ __launch_bounds__(256) void k_h2(const float* __restrict__ spk,
                                            const float* __restrict__ W2,
                                            const float* __restrict__ b2,
                                            float* __restrict__ h2) {
#pragma clang fp contract(off)
    const int lane = threadIdx.x & 63;
    const int wave = threadIdx.x >> 6;
    size_t tb = (size_t)blockIdx.x * 4 + wave;    // t*B + b
    const float* row = spk + tb * HID;
    float s0 = 0.0f, s1 = 0.0f;
#pragma unroll
    for (int c = 0; c < 16; ++c) {
        float v  = row[c * 64 + lane];
        float r0 = v * W2[c * 64 + lane];
        float r1 = v * W2[HID + c * 64 + lane];
#pragma unroll
        for (int off = 32; off > 0; off >>= 1) {
            r0 += __shfl_xor(r0, off, 64);
            r1 += __shfl_xor(r1, off, 64);
        }
        s0 += r0;
        s1 += r1;
    }
    s0 += b2[0];
    s1 += b2[1];
    if (lane == 0)
        *reinterpret_cast<float2*>(h2 + tb * 2) = make_float2(s0, s1);
}

__global__ __launch_bounds__(256) void k_scan(const float* __restrict__ h2,
                                              float* __restrict__ outSpk,
                                              float* __restrict__ outMem2) {
#pragma clang fp contract(off)
    const int tid = threadIdx.x;                  // b*2 + o
    float mem = 0.0f;
    float cur[8], nxt[8];
#pragma unroll
    for (int k = 0; k < 8; ++k) cur[k] = h2[k * 256 + tid];
    for (int t0 = 0; t0 < TT; t0 += 8) {
#pragma unroll
        for (int k = 0; k < 8; ++k) {
            int tn = t0 + 8 + k;
            nxt[k] = (tn < TT) ? h2[tn * 256 + tid] : 0.0f;
        }
#pragma unroll
        for (int k = 0; k < 8; ++k) {
            float mm = 0.9f * mem;
            mm = mm + cur[k];
            float spk = (mm - 1.0f > 0.0f) ? 1.0f : 0.0f;
            mm = mm - spk;
            mem = mm;
            outSpk[(t0 + k) * 256 + tid] = spk;
        }
#pragma unroll
        for (int k = 0; k < 8; ++k) cur[k] = nxt[k];
    }
    outMem2[tid] = mem;
}

extern "C" void kernel_launch(void* const* d_in, const int* in_sizes, int n_in,
                              void* d_out, int out_size, void* d_ws, size_t ws_size,
                              hipStream_t stream) {
    const float* x  = (const float*)d_in[0];
    const float* W1 = (const float*)d_in[1];
    const float* b1 = (const float*)d_in[2];
    const float* W2 = (const float*)d_in[3];
    const float* b2 = (const float*)d_in[4];
    float* out = (float*)d_out;

    char* ws = (char*)d_ws;
    float*         W1T = (float*)(ws);                                 // 257 rows ~1.03 MB
    unsigned int*  cnt = (unsigned int*)(ws + (2 << 20));              // 512 KB
    unsigned char* idx = (unsigned char*)(ws + (2 << 20) + (1 << 19)); // 131072*slots

    // size the index lists to the workspace (fallback path covers overflow)
    size_t fixedB = (size_t)(2 << 20) + (1 << 19) + (1 << 20);
    size_t avail  = ws_size > fixedB ? ws_size - fixedB : 0;
    long   s      = (long)((avail / 131072) & ~(size_t)7);
    int slots = (int)(s > 96 ? 96 : (s < 8 ? 8 : s));

    float* h2 = (float*)(ws + (2 << 20) + (1 << 19) + (size_t)131072 * (size_t)slots); // 1 MB

    k_transpose<<<1028, 256, 0, stream>>>(W1, W1T);
    k_pack<<<131072, 256, 0, stream>>>(x, cnt, idx, slots);
    k_snn<<<512, 256, 0, stream>>>(W1T, cnt, idx, x, b1, out + OFF_HID, slots);
    k_h2<<<32768, 256, 0, stream>>>(out + OFF_HID, W2, b2, h2);
    k_scan<<<1, 256, 0, stream>>>(h2, out, out + OFF_MEM2);
}